// Round 11
// baseline (329.170 us; speedup 1.0000x reference)
//
#include <hip/hip_runtime.h>

#define N_NODES 50000
#define N_EDGES 1600000
#define DIM 128
#define M_PAD 50048    // 782 * 64
#define SCAN_NB ((N_NODES + 255) / 256)   // 196

// ---------------- workspace layout (bytes) ----------------
// C layout per node: 1024 B = [Q: 128 fp32 | u32 0..127][K: 128 fp8 | u32 128..159]
//                             [V: 128 bf16 | u32 160..223][pad u32 224..255]
#define OFF_WCATB  0UL                    // 384*128*2     = 98304
#define OFF_BCAT   98304UL                // 384*4         = 1536
#define OFF_XB     99840UL                // 50048*128*2   = 12812288
#define OFF_C      12912128UL             // 50000*1024    = 51200000
#define OFF_SRC    64112128UL             // 1600000*2     = 3200000   (csr src ids, u16)
#define OFF_RANK   67312128UL             // 1600000*2     = 3200000   (edge rank within dst row)
#define OFF_RS     70512128UL             // 50001*4       = 200004
#define OFF_CNT    70712136UL             // 50000*4       = 200000
#define OFF_BSUM   70912136UL             // 256*4         = 1024
#define OFF_AGG    70913168UL             // 50000*128*4   = 25600000  -> total ~96.5 MB

typedef __attribute__((ext_vector_type(8))) short short8;    // 8 bf16
typedef __attribute__((ext_vector_type(4))) float floatx4;   // MFMA acc

__device__ __forceinline__ unsigned bf16r(float f) {   // fp32 -> bf16 bits, RNE
    unsigned u = __float_as_uint(f);
    return (u + 0x7fffu + ((u >> 16) & 1u)) >> 16;
}
__device__ __forceinline__ unsigned pack2(float a, float b) {
    return bf16r(a) | (bf16r(b) << 16);
}
__device__ __forceinline__ float blo(unsigned v) { return __uint_as_float(v << 16); }
__device__ __forceinline__ float bhi(unsigned v) { return __uint_as_float(v & 0xffff0000u); }

// ---- dispatch 1: hist(+rank) 1:1-interleaved with x->bf16 cvt, + weight prep ----
// hist (atomic-latency-bound) and cvt/prepw (BW-bound) are mutually independent;
// co-residency hides the cheap prep under the ~75us atomic pole.
#define PH_PAIRS 6250       // 6250 hist blocks + 6250 cvt blocks
#define PREPW_NB 192
#define PH_GRID (2 * PH_PAIRS + PREPW_NB)
__global__ __launch_bounds__(256) void k_prep_hist(const float* __restrict__ x,
                                                   unsigned short* __restrict__ xb,
                                                   const float* __restrict__ Wq, const float* __restrict__ bq,
                                                   const float* __restrict__ Wk, const float* __restrict__ bk,
                                                   const float* __restrict__ Wv, const float* __restrict__ bv,
                                                   unsigned short* __restrict__ Wcatb,
                                                   float* __restrict__ bcat,
                                                   const int* __restrict__ dstA,
                                                   int* __restrict__ counts,
                                                   unsigned short* __restrict__ rank16) {
    int bx = blockIdx.x, t = threadIdx.x;
    if (bx < 2 * PH_PAIRS) {
        int pair = bx >> 1;
        if (bx & 1) {                       // cvt: one float4 per thread
            int i = pair * 256 + t;
            if (i < N_NODES * DIM / 4) {
                float4 f = ((const float4*)x)[i];
                ushort4 o;
                o.x = (unsigned short)bf16r(f.x); o.y = (unsigned short)bf16r(f.y);
                o.z = (unsigned short)bf16r(f.z); o.w = (unsigned short)bf16r(f.w);
                ((ushort4*)xb)[i] = o;
            }
        } else {                            // hist + rank
            int e = pair * 256 + t;
            if (e < N_EDGES) rank16[e] = (unsigned short)atomicAdd(&counts[dstA[e]], 1);
        }
    } else {
        int i = (bx - 2 * PH_PAIRS) * 256 + t;
        if (i < 3 * DIM * DIM) {
            int ro = i >> 7, col = i & 127;
            const float* W = (ro < 128) ? Wq : (ro < 256) ? Wk : Wv;
            Wcatb[i] = (unsigned short)bf16r(W[(ro & 127) * DIM + col]);
        }
        if (i < 3 * DIM) {
            const float* b = (i < 128) ? bq : (i < 256) ? bk : bv;
            bcat[i] = b[i & 127];
        }
    }
}

// ---- hierarchical exclusive scan of counts[50000] ----
__global__ __launch_bounds__(256) void k_scanA(const int* __restrict__ counts,
                                               int* __restrict__ bsum) {
    __shared__ int red[256];
    int t = threadIdx.x, i = blockIdx.x * 256 + t;
    red[t] = (i < N_NODES) ? counts[i] : 0;
    __syncthreads();
    for (int off = 128; off > 0; off >>= 1) {
        if (t < off) red[t] += red[t + off];
        __syncthreads();
    }
    if (t == 0) bsum[blockIdx.x] = red[0];
}
__global__ __launch_bounds__(256) void k_scanB(int* __restrict__ bsum, int nb) {
    __shared__ int s[256];
    int t = threadIdx.x;
    int v = (t < nb) ? bsum[t] : 0;
    s[t] = v;
    __syncthreads();
    for (int off = 1; off < 256; off <<= 1) {
        int u = (t >= off) ? s[t - off] : 0;
        __syncthreads();
        s[t] += u;
        __syncthreads();
    }
    if (t < nb) bsum[t] = s[t] - v;   // exclusive
}
__global__ __launch_bounds__(256) void k_scanC(const int* __restrict__ counts,
                                               const int* __restrict__ bsum,
                                               int* __restrict__ row_start) {
    __shared__ int s[256];
    int t = threadIdx.x, i = blockIdx.x * 256 + t;
    int v = (i < N_NODES) ? counts[i] : 0;
    s[t] = v;
    __syncthreads();
    for (int off = 1; off < 256; off <<= 1) {
        int u = (t >= off) ? s[t - off] : 0;
        __syncthreads();
        s[t] += u;
        __syncthreads();
    }
    int excl = bsum[blockIdx.x] + s[t] - v;
    if (i < N_NODES) {
        row_start[i] = excl;
        if (i == N_NODES - 1) row_start[N_NODES] = excl + v;
    }
}

// ---- dispatch 3: QKV MFMA GEMM 3:4-interleaved with atomic-free CSR fill ----
// GEMM is MFMA-pipe-bound (~28us), fill is scatter-latency-bound; independent
// (GEMM: xb,Wcatb -> Cu; fill: srcA,dstA,row_start,rank16 -> csr_src).
#define GQ_MB (M_PAD / 64)          // 782
#define GQ_BLOCKS (GQ_MB * 6)       // 4692 = 3 * 1564
#define FILL_NB 6250
#define GF_GRPS 1564
#define GF_GRID (GF_GRPS * 7)       // 10948
__global__ __launch_bounds__(256) void k_gemmqkv_fill(const unsigned short* __restrict__ xb,
                                                      const unsigned short* __restrict__ Wb,
                                                      const float* __restrict__ bias,
                                                      unsigned* __restrict__ Cu, int M,
                                                      const int* __restrict__ srcA,
                                                      const int* __restrict__ dstA,
                                                      const int* __restrict__ row_start,
                                                      const unsigned short* __restrict__ rank16,
                                                      unsigned short* __restrict__ csr_src) {
    __shared__ __align__(16) unsigned short As[64][136];
    __shared__ __align__(16) unsigned short Bs[64][136];
    const int grp = blockIdx.x / 7, r = blockIdx.x % 7;
    if (r < 4) {                            // fill
        int fb = grp * 4 + r;
        if (fb < FILL_NB) {
            int e = fb * 256 + threadIdx.x;
            if (e < N_EDGES) {
                int d = dstA[e];
                csr_src[row_start[d] + rank16[e]] = (unsigned short)srcA[e];
            }
        }
        return;
    }
    const int g = grp * 3 + (r - 4);
    if (g >= GQ_BLOCKS) return;
    const int m0 = (g % GQ_MB) * 64, n0 = (g / GQ_MB) * 64;
    const int t = threadIdx.x;
    {
        int row = t >> 2, ch = t & 3;
        const uint4* xrow = (const uint4*)(xb + (long)(m0 + row) * 128);
        const uint4* wrow = (const uint4*)(Wb + (long)(n0 + row) * 128);
#pragma unroll
        for (int j = 0; j < 4; ++j) {
            *(uint4*)&As[row][(ch + 4 * j) * 8] = xrow[ch + 4 * j];
            *(uint4*)&Bs[row][(ch + 4 * j) * 8] = wrow[ch + 4 * j];
        }
    }
    __syncthreads();
    const int w = t >> 6, lane = t & 63;
    const int quad = lane >> 4, c = lane & 15;
    floatx4 acc[4] = {{0.f,0.f,0.f,0.f},{0.f,0.f,0.f,0.f},{0.f,0.f,0.f,0.f},{0.f,0.f,0.f,0.f}};
#pragma unroll
    for (int ks = 0; ks < 4; ++ks) {
        short8 a = *(const short8*)&As[w * 16 + c][ks * 32 + quad * 8];
#pragma unroll
        for (int nt = 0; nt < 4; ++nt) {
            short8 b = *(const short8*)&Bs[nt * 16 + c][ks * 32 + quad * 8];
            acc[nt] = __builtin_amdgcn_mfma_f32_16x16x32_bf16(a, b, acc[nt], 0, 0, 0);
        }
    }
#pragma unroll
    for (int nt = 0; nt < 4; ++nt) {
        int gn = n0 + nt * 16 + c;
        float bv = bias[gn];
        int slice = gn >> 7;           // 0=Q 1=K(fp8) 2=V(bf16)
        int cs = gn & 127;
#pragma unroll
        for (int i = 0; i < 4; ++i) {
            int gm = m0 + w * 16 + quad * 4 + i;
            float o = acc[nt][i] + bv;
            float f1 = __shfl_xor(o, 1);
            float f2 = __shfl_xor(o, 2);
            float f3 = __shfl_xor(o, 3);
            if (gm < M) {
                unsigned* crow = Cu + (long)gm * 256;
                if (slice == 0) {
                    ((float*)crow)[cs] = o;
                } else if (slice == 1) {
                    if ((c & 3) == 0) {     // pack 4 cols -> 4 fp8 in one u32
                        int pk = __builtin_amdgcn_cvt_pk_fp8_f32(o, f1, 0, false);
                        pk = __builtin_amdgcn_cvt_pk_fp8_f32(f2, f3, pk, true);
                        crow[128 + (cs >> 2)] = (unsigned)pk;
                    }
                } else {
                    if ((c & 1) == 0) crow[160 + (cs >> 1)] = pack2(o, f1);
                }
            }
        }
    }
}

// ---- fused scores+softmax+aggregate, half-wave layout, no max shift ----
__global__ __launch_bounds__(256) void k_attn(const unsigned* __restrict__ Cu,
                                              const int* __restrict__ row_start,
                                              const unsigned short* __restrict__ csr_src,
                                              float* __restrict__ agg) {
    int d = blockIdx.x * 4 + (threadIdx.x >> 6);
    int lane = threadIdx.x & 63;
    if (d >= N_NODES) return;
    const int half = lane >> 5, sl = lane & 31;
    const float scale = 0.17677669529663687f;   // 1/sqrt(32), folded into q
    float4 q4 = *(const float4*)((const float*)(Cu + (long)d * 256) + 4 * sl);
    q4.x *= scale; q4.y *= scale; q4.z *= scale; q4.w *= scale;
    int s0 = row_start[d], s1 = row_start[d + 1];
    float lsum = 0.f, a0 = 0.f, a1 = 0.f, a2 = 0.f, a3 = 0.f;
    int pos = s0;
    for (; pos + 4 <= s1; pos += 4) {         // 2 edges per half
        int sa = csr_src[pos + half];
        int sb = csr_src[pos + 2 + half];
        const unsigned* ra = Cu + (long)sa * 256;
        const unsigned* rb = Cu + (long)sb * 256;
        unsigned ka = ra[128 + sl];
        unsigned kb = rb[128 + sl];
        uint2 va = *(const uint2*)(ra + 160 + 2 * sl);
        uint2 vb = *(const uint2*)(rb + 160 + 2 * sl);
        float pa = q4.x * __builtin_amdgcn_cvt_f32_fp8(ka, 0)
                 + q4.y * __builtin_amdgcn_cvt_f32_fp8(ka, 1)
                 + q4.z * __builtin_amdgcn_cvt_f32_fp8(ka, 2)
                 + q4.w * __builtin_amdgcn_cvt_f32_fp8(ka, 3);
        float pb = q4.x * __builtin_amdgcn_cvt_f32_fp8(kb, 0)
                 + q4.y * __builtin_amdgcn_cvt_f32_fp8(kb, 1)
                 + q4.z * __builtin_amdgcn_cvt_f32_fp8(kb, 2)
                 + q4.w * __builtin_amdgcn_cvt_f32_fp8(kb, 3);
        pa += __shfl_xor(pa, 1); pa += __shfl_xor(pa, 2); pa += __shfl_xor(pa, 4);
        pb += __shfl_xor(pb, 1); pb += __shfl_xor(pb, 2); pb += __shfl_xor(pb, 4);
        float wa = __expf(pa), wb = __expf(pb);
        lsum += wa + wb;
        a0 += wa * blo(va.x) + wb * blo(vb.x);
        a1 += wa * bhi(va.x) + wb * bhi(vb.x);
        a2 += wa * blo(va.y) + wb * blo(vb.y);
        a3 += wa * bhi(va.y) + wb * bhi(vb.y);
    }
    for (; pos < s1; pos += 2) {              // tail: 1 edge per half, predicated
        int e = pos + half;
        bool ok = e < s1;
        int sa = csr_src[ok ? e : (s1 - 1)];
        const unsigned* ra = Cu + (long)sa * 256;
        unsigned ka = ra[128 + sl];
        uint2 va = *(const uint2*)(ra + 160 + 2 * sl);
        float pa = q4.x * __builtin_amdgcn_cvt_f32_fp8(ka, 0)
                 + q4.y * __builtin_amdgcn_cvt_f32_fp8(ka, 1)
                 + q4.z * __builtin_amdgcn_cvt_f32_fp8(ka, 2)
                 + q4.w * __builtin_amdgcn_cvt_f32_fp8(ka, 3);
        pa += __shfl_xor(pa, 1); pa += __shfl_xor(pa, 2); pa += __shfl_xor(pa, 4);
        float wa = ok ? __expf(pa) : 0.f;
        lsum += wa;
        a0 += wa * blo(va.x);
        a1 += wa * bhi(va.x);
        a2 += wa * blo(va.y);
        a3 += wa * bhi(va.y);
    }
    lsum += __shfl_xor(lsum, 32);
    a0 += __shfl_xor(a0, 32);
    a1 += __shfl_xor(a1, 32);
    a2 += __shfl_xor(a2, 32);
    a3 += __shfl_xor(a3, 32);
    if (lane < 32) {
        float inv = 1.f / (lsum + 1e-8f);
        float4 o;
        o.x = a0 * inv; o.y = a1 * inv; o.z = a2 * inv; o.w = a3 * inv;
        *(float4*)&agg[(long)d * 128 + 4 * sl] = o;
    }
}

// Output GEMM (fp32): out = relu(A[M x 128] @ B[128 x 128]^T + bias)
__global__ __launch_bounds__(256) void k_gemm(const float* __restrict__ A,
                                              const float* __restrict__ B,
                                              const float* __restrict__ bias,
                                              float* __restrict__ Cp, int M) {
    __shared__ float As[32][64];
    __shared__ float Bs[32][64];
    const int m0 = blockIdx.x * 64, n0 = blockIdx.y * 64;
    const int t = threadIdx.x;
    const int tm = (t & 15) * 4, tn = (t >> 4) * 4;
    float acc[4][4] = {};
    for (int k0 = 0; k0 < 128; k0 += 32) {
#pragma unroll
        for (int i = 0; i < 2; ++i) {
            int idx = t + i * 256;
            int row = idx >> 3;
            int c4 = (idx & 7) * 4;
            float4 fa = make_float4(0.f, 0.f, 0.f, 0.f);
            if (m0 + row < M) fa = *(const float4*)&A[(long)(m0 + row) * 128 + k0 + c4];
            As[c4 + 0][row] = fa.x; As[c4 + 1][row] = fa.y;
            As[c4 + 2][row] = fa.z; As[c4 + 3][row] = fa.w;
            float4 fb = *(const float4*)&B[(long)(n0 + row) * 128 + k0 + c4];
            Bs[c4 + 0][row] = fb.x; Bs[c4 + 1][row] = fb.y;
            Bs[c4 + 2][row] = fb.z; Bs[c4 + 3][row] = fb.w;
        }
        __syncthreads();
#pragma unroll
        for (int k = 0; k < 32; ++k) {
            float4 a = *(const float4*)&As[k][tm];
            float4 b = *(const float4*)&Bs[k][tn];
            acc[0][0] += a.x * b.x; acc[0][1] += a.x * b.y; acc[0][2] += a.x * b.z; acc[0][3] += a.x * b.w;
            acc[1][0] += a.y * b.x; acc[1][1] += a.y * b.y; acc[1][2] += a.y * b.z; acc[1][3] += a.y * b.w;
            acc[2][0] += a.z * b.x; acc[2][1] += a.z * b.y; acc[2][2] += a.z * b.z; acc[2][3] += a.z * b.w;
            acc[3][0] += a.w * b.x; acc[3][1] += a.w * b.y; acc[3][2] += a.w * b.z; acc[3][3] += a.w * b.w;
        }
        __syncthreads();
    }
    float4 bv4 = *(const float4*)&bias[n0 + tn];
#pragma unroll
    for (int i = 0; i < 4; ++i) {
        int m = m0 + tm + i;
        if (m >= M) continue;
        float4 o;
        o.x = fmaxf(acc[i][0] + bv4.x, 0.f); o.y = fmaxf(acc[i][1] + bv4.y, 0.f);
        o.z = fmaxf(acc[i][2] + bv4.z, 0.f); o.w = fmaxf(acc[i][3] + bv4.w, 0.f);
        *(float4*)&Cp[(long)m * 128 + n0 + tn] = o;
    }
}

extern "C" void kernel_launch(void* const* d_in, const int* in_sizes, int n_in,
                              void* d_out, int out_size, void* d_ws, size_t ws_size,
                              hipStream_t stream) {
    const float* x  = (const float*)d_in[0];
    const int* edge = (const int*)d_in[1];
    const float* Wq = (const float*)d_in[2];
    const float* bq = (const float*)d_in[3];
    const float* Wk = (const float*)d_in[4];
    const float* bk = (const float*)d_in[5];
    const float* Wv = (const float*)d_in[6];
    const float* bv = (const float*)d_in[7];
    const float* Wo = (const float*)d_in[8];
    const float* bo = (const float*)d_in[9];
    float* out = (float*)d_out;

    char* ws = (char*)d_ws;
    unsigned short* Wcatb = (unsigned short*)(ws + OFF_WCATB);
    float* bcat      = (float*)(ws + OFF_BCAT);
    unsigned short* xb = (unsigned short*)(ws + OFF_XB);
    unsigned* Cu     = (unsigned*)(ws + OFF_C);
    unsigned short* csr_src = (unsigned short*)(ws + OFF_SRC);
    unsigned short* rank16  = (unsigned short*)(ws + OFF_RANK);
    int*   row_start = (int*)(ws + OFF_RS);
    int*   counts    = (int*)(ws + OFF_CNT);
    int*   bsum      = (int*)(ws + OFF_BSUM);
    float* agg       = (float*)(ws + OFF_AGG);

    const int* srcA = edge;
    const int* dstA = edge + N_EDGES;

    hipMemsetAsync(counts, 0, N_NODES * 4, stream);

    // D1: histogram(+rank) || x->bf16 || weight prep
    k_prep_hist<<<PH_GRID, 256, 0, stream>>>(
        x, xb, Wq, bq, Wk, bk, Wv, bv, Wcatb, bcat, dstA, counts, rank16);

    // D2: scan -> row_start
    k_scanA<<<SCAN_NB, 256, 0, stream>>>(counts, bsum);
    k_scanB<<<1, 256, 0, stream>>>(bsum, SCAN_NB);
    k_scanC<<<SCAN_NB, 256, 0, stream>>>(counts, bsum, row_start);

    // D3: QKV MFMA GEMM || atomic-free CSR fill
    k_gemmqkv_fill<<<GF_GRID, 256, 0, stream>>>(
        xb, Wcatb, bcat, Cu, N_NODES, srcA, dstA, row_start, rank16, csr_src);

    // D4: fused scores + softmax + V aggregate
    k_attn<<<(N_NODES + 3) / 4, 256, 0, stream>>>(Cu, row_start, csr_src, agg);

    // D5: out = relu(agg @ Wo^T + bo)
    k_gemm<<<dim3((N_NODES + 63) / 64, 2), 256, 0, stream>>>(agg, Wo, bo, out, N_NODES);
}

// Round 12
// 313.096 us; speedup vs baseline: 1.0513x; 1.0513x over previous
//
#include <hip/hip_runtime.h>

#define N_NODES 50000
#define N_EDGES 1600000
#define DIM 128
#define M_PAD 50048    // 782 * 64
#define SCAN_NB ((N_NODES + 255) / 256)   // 196

// ---------------- workspace layout (bytes) ----------------
// C layout per node: 1024 B = [Q: 128 fp32 | u32 0..127][K: 128 fp8 | u32 128..159]
//                             [V: 128 bf16 | u32 160..223][pad u32 224..255]
#define OFF_WCATB  0UL                    // 384*128*2     = 98304
#define OFF_BCAT   98304UL                // 384*4         = 1536
#define OFF_XB     99840UL                // 50048*128*2   = 12812288
#define OFF_C      12912128UL             // 50000*1024    = 51200000
#define OFF_SRC    64112128UL             // 1600000*2     = 3200000   (csr src ids, u16)
#define OFF_RANK   67312128UL             // 1600000*2     = 3200000   (edge rank within dst row)
#define OFF_RS     70512128UL             // 50001*4       = 200004
#define OFF_CNT    70712136UL             // 50000*4       = 200000
#define OFF_BSUM   70912136UL             // 256*4         = 1024
#define OFF_AGG    70913168UL             // 50000*128*4   = 25600000  -> total ~96.5 MB

typedef __attribute__((ext_vector_type(8))) short short8;    // 8 bf16
typedef __attribute__((ext_vector_type(4))) float floatx4;   // MFMA acc
typedef __attribute__((ext_vector_type(2))) float fx2;       // packed fp8 cvt result

__device__ __forceinline__ unsigned bf16r(float f) {   // fp32 -> bf16 bits, RNE
    unsigned u = __float_as_uint(f);
    return (u + 0x7fffu + ((u >> 16) & 1u)) >> 16;
}
__device__ __forceinline__ unsigned pack2(float a, float b) {
    return bf16r(a) | (bf16r(b) << 16);
}
__device__ __forceinline__ float blo(unsigned v) { return __uint_as_float(v << 16); }
__device__ __forceinline__ float bhi(unsigned v) { return __uint_as_float(v & 0xffff0000u); }

// ---- fused prep: cvtx blocks | zero-counts blocks | prepw blocks ----
#define CVT_NB 6250         // 1.6M float4s
#define ZERO_NB SCAN_NB     // 196
#define PREPW_NB 192        // 49152 threads
__global__ __launch_bounds__(256) void k_prep(const float* __restrict__ x,
                                              unsigned short* __restrict__ xb,
                                              int* __restrict__ counts,
                                              const float* __restrict__ Wq, const float* __restrict__ bq,
                                              const float* __restrict__ Wk, const float* __restrict__ bk,
                                              const float* __restrict__ Wv, const float* __restrict__ bv,
                                              unsigned short* __restrict__ Wcatb,
                                              float* __restrict__ bcat) {
    int bx = blockIdx.x, t = threadIdx.x;
    if (bx < CVT_NB) {
        int i = bx * 256 + t;
        if (i < N_NODES * DIM / 4) {
            float4 f = ((const float4*)x)[i];
            ushort4 o;
            o.x = (unsigned short)bf16r(f.x); o.y = (unsigned short)bf16r(f.y);
            o.z = (unsigned short)bf16r(f.z); o.w = (unsigned short)bf16r(f.w);
            ((ushort4*)xb)[i] = o;
        }
    } else if (bx < CVT_NB + ZERO_NB) {
        int i = (bx - CVT_NB) * 256 + t;
        if (i < N_NODES) counts[i] = 0;
    } else {
        int i = (bx - CVT_NB - ZERO_NB) * 256 + t;
        if (i < 3 * DIM * DIM) {
            int ro = i >> 7, col = i & 127;
            const float* W = (ro < 128) ? Wq : (ro < 256) ? Wk : Wv;
            Wcatb[i] = (unsigned short)bf16r(W[(ro & 127) * DIM + col]);
        }
        if (i < 3 * DIM) {
            const float* b = (i < 128) ? bq : (i < 256) ? bk : bv;
            bcat[i] = b[i & 127];
        }
    }
}

// ---- fused QKV MFMA GEMM + dst histogram(+rank), INTERLEAVED 3:4 ----
// (round-10 arrangement — empirically best: the atomic-bound hist overlaps
// the MFMA-bound GEMM; combined dispatch ~ max, not sum)
#define GQ_MB (M_PAD / 64)          // 782
#define GQ_BLOCKS (GQ_MB * 6)       // 4692 = 3 * 1564
#define HIST_NB 6250
#define GQH_GRID (1564 * 7)         // 10948
__global__ __launch_bounds__(256) void k_gemmqkv_hist(const unsigned short* __restrict__ xb,
                                                      const unsigned short* __restrict__ Wb,
                                                      const float* __restrict__ bias,
                                                      unsigned* __restrict__ Cu, int M,
                                                      const int* __restrict__ dstA,
                                                      int* __restrict__ counts,
                                                      unsigned short* __restrict__ rank16) {
    __shared__ __align__(16) unsigned short As[64][136];
    __shared__ __align__(16) unsigned short Bs[64][136];
    const int grp = blockIdx.x / 7, r = blockIdx.x % 7;
    if (r >= 3) {
        int h = grp * 4 + (r - 3);
        if (h < HIST_NB) {
            int e = h * 256 + threadIdx.x;
            if (e < N_EDGES) rank16[e] = (unsigned short)atomicAdd(&counts[dstA[e]], 1);
        }
        return;
    }
    const int g = grp * 3 + r;
    const int m0 = (g % GQ_MB) * 64, n0 = (g / GQ_MB) * 64;
    const int t = threadIdx.x;
    {
        int row = t >> 2, ch = t & 3;
        const uint4* xrow = (const uint4*)(xb + (long)(m0 + row) * 128);
        const uint4* wrow = (const uint4*)(Wb + (long)(n0 + row) * 128);
#pragma unroll
        for (int j = 0; j < 4; ++j) {
            *(uint4*)&As[row][(ch + 4 * j) * 8] = xrow[ch + 4 * j];
            *(uint4*)&Bs[row][(ch + 4 * j) * 8] = wrow[ch + 4 * j];
        }
    }
    __syncthreads();
    const int w = t >> 6, lane = t & 63;
    const int quad = lane >> 4, c = lane & 15;
    floatx4 acc[4] = {{0.f,0.f,0.f,0.f},{0.f,0.f,0.f,0.f},{0.f,0.f,0.f,0.f},{0.f,0.f,0.f,0.f}};
#pragma unroll
    for (int ks = 0; ks < 4; ++ks) {
        short8 a = *(const short8*)&As[w * 16 + c][ks * 32 + quad * 8];
#pragma unroll
        for (int nt = 0; nt < 4; ++nt) {
            short8 b = *(const short8*)&Bs[nt * 16 + c][ks * 32 + quad * 8];
            acc[nt] = __builtin_amdgcn_mfma_f32_16x16x32_bf16(a, b, acc[nt], 0, 0, 0);
        }
    }
#pragma unroll
    for (int nt = 0; nt < 4; ++nt) {
        int gn = n0 + nt * 16 + c;
        float bv = bias[gn];
        int slice = gn >> 7;           // 0=Q 1=K(fp8) 2=V(bf16)
        int cs = gn & 127;
#pragma unroll
        for (int i = 0; i < 4; ++i) {
            int gm = m0 + w * 16 + quad * 4 + i;
            float o = acc[nt][i] + bv;
            float f1 = __shfl_xor(o, 1);
            float f2 = __shfl_xor(o, 2);
            float f3 = __shfl_xor(o, 3);
            if (gm < M) {
                unsigned* crow = Cu + (long)gm * 256;
                if (slice == 0) {
                    ((float*)crow)[cs] = o;
                } else if (slice == 1) {
                    if ((c & 3) == 0) {     // pack 4 cols -> 4 fp8 in one u32
                        int pk = __builtin_amdgcn_cvt_pk_fp8_f32(o, f1, 0, false);
                        pk = __builtin_amdgcn_cvt_pk_fp8_f32(f2, f3, pk, true);
                        crow[128 + (cs >> 2)] = (unsigned)pk;
                    }
                } else {
                    if ((c & 1) == 0) crow[160 + (cs >> 1)] = pack2(o, f1);
                }
            }
        }
    }
}

// ---- hierarchical exclusive scan of counts[50000] ----
__global__ __launch_bounds__(256) void k_scanA(const int* __restrict__ counts,
                                               int* __restrict__ bsum) {
    __shared__ int red[256];
    int t = threadIdx.x, i = blockIdx.x * 256 + t;
    red[t] = (i < N_NODES) ? counts[i] : 0;
    __syncthreads();
    for (int off = 128; off > 0; off >>= 1) {
        if (t < off) red[t] += red[t + off];
        __syncthreads();
    }
    if (t == 0) bsum[blockIdx.x] = red[0];
}
__global__ __launch_bounds__(256) void k_scanB(int* __restrict__ bsum, int nb) {
    __shared__ int s[256];
    int t = threadIdx.x;
    int v = (t < nb) ? bsum[t] : 0;
    s[t] = v;
    __syncthreads();
    for (int off = 1; off < 256; off <<= 1) {
        int u = (t >= off) ? s[t - off] : 0;
        __syncthreads();
        s[t] += u;
        __syncthreads();
    }
    if (t < nb) bsum[t] = s[t] - v;   // exclusive
}
__global__ __launch_bounds__(256) void k_scanC(const int* __restrict__ counts,
                                               const int* __restrict__ bsum,
                                               int* __restrict__ row_start) {
    __shared__ int s[256];
    int t = threadIdx.x, i = blockIdx.x * 256 + t;
    int v = (i < N_NODES) ? counts[i] : 0;
    s[t] = v;
    __syncthreads();
    for (int off = 1; off < 256; off <<= 1) {
        int u = (t >= off) ? s[t - off] : 0;
        __syncthreads();
        s[t] += u;
        __syncthreads();
    }
    int excl = bsum[blockIdx.x] + s[t] - v;
    if (i < N_NODES) {
        row_start[i] = excl;
        if (i == N_NODES - 1) row_start[N_NODES] = excl + v;
    }
}

// Atomic-free CSR fill: pure scatter using precomputed rank.
__global__ void k_fill(const int* __restrict__ srcA, const int* __restrict__ dstA,
                       const int* __restrict__ row_start,
                       const unsigned short* __restrict__ rank16,
                       unsigned short* __restrict__ csr_src) {
    int e = blockIdx.x * blockDim.x + threadIdx.x;
    if (e < N_EDGES) {
        int d = dstA[e];
        csr_src[row_start[d] + rank16[e]] = (unsigned short)srcA[e];
    }
}

// ---- fused scores+softmax+aggregate, half-wave layout, no max shift ----
// Half h = lane>>5 owns 4 edges/iter; sub-lane sl = lane&31 owns dims
// 4sl..4sl+3. Packed fp8->f32 cvt (2/instr); 12 gathers in flight per half.
__global__ __launch_bounds__(256) void k_attn(const unsigned* __restrict__ Cu,
                                              const int* __restrict__ row_start,
                                              const unsigned short* __restrict__ csr_src,
                                              float* __restrict__ agg) {
    int d = blockIdx.x * 4 + (threadIdx.x >> 6);
    int lane = threadIdx.x & 63;
    if (d >= N_NODES) return;
    const int half = lane >> 5, sl = lane & 31;
    const float scale = 0.17677669529663687f;   // 1/sqrt(32), folded into q
    float4 q4 = *(const float4*)((const float*)(Cu + (long)d * 256) + 4 * sl);
    q4.x *= scale; q4.y *= scale; q4.z *= scale; q4.w *= scale;
    int s0 = row_start[d], s1 = row_start[d + 1];
    float lsum = 0.f, a0 = 0.f, a1 = 0.f, a2 = 0.f, a3 = 0.f;
    int pos = s0;
    for (; pos + 8 <= s1; pos += 8) {         // 4 edges per half
        int base = pos + half * 4;
        int sa = csr_src[base + 0];
        int sb = csr_src[base + 1];
        int sc2 = csr_src[base + 2];
        int sd = csr_src[base + 3];
        const unsigned* ra = Cu + (long)sa * 256;
        const unsigned* rb = Cu + (long)sb * 256;
        const unsigned* rc = Cu + (long)sc2 * 256;
        const unsigned* rd = Cu + (long)sd * 256;
        unsigned ka = ra[128 + sl];
        unsigned kb = rb[128 + sl];
        unsigned kc = rc[128 + sl];
        unsigned kd = rd[128 + sl];
        uint2 va = *(const uint2*)(ra + 160 + 2 * sl);
        uint2 vb = *(const uint2*)(rb + 160 + 2 * sl);
        uint2 vc = *(const uint2*)(rc + 160 + 2 * sl);
        uint2 vd = *(const uint2*)(rd + 160 + 2 * sl);
        fx2 a01 = __builtin_amdgcn_cvt_pk_f32_fp8((int)ka, false);
        fx2 a23 = __builtin_amdgcn_cvt_pk_f32_fp8((int)ka, true);
        fx2 b01 = __builtin_amdgcn_cvt_pk_f32_fp8((int)kb, false);
        fx2 b23 = __builtin_amdgcn_cvt_pk_f32_fp8((int)kb, true);
        fx2 c01 = __builtin_amdgcn_cvt_pk_f32_fp8((int)kc, false);
        fx2 c23 = __builtin_amdgcn_cvt_pk_f32_fp8((int)kc, true);
        fx2 d01 = __builtin_amdgcn_cvt_pk_f32_fp8((int)kd, false);
        fx2 d23 = __builtin_amdgcn_cvt_pk_f32_fp8((int)kd, true);
        float pa = q4.x * a01.x + q4.y * a01.y + q4.z * a23.x + q4.w * a23.y;
        float pb = q4.x * b01.x + q4.y * b01.y + q4.z * b23.x + q4.w * b23.y;
        float pc = q4.x * c01.x + q4.y * c01.y + q4.z * c23.x + q4.w * c23.y;
        float pd = q4.x * d01.x + q4.y * d01.y + q4.z * d23.x + q4.w * d23.y;
        pa += __shfl_xor(pa, 1); pa += __shfl_xor(pa, 2); pa += __shfl_xor(pa, 4);
        pb += __shfl_xor(pb, 1); pb += __shfl_xor(pb, 2); pb += __shfl_xor(pb, 4);
        pc += __shfl_xor(pc, 1); pc += __shfl_xor(pc, 2); pc += __shfl_xor(pc, 4);
        pd += __shfl_xor(pd, 1); pd += __shfl_xor(pd, 2); pd += __shfl_xor(pd, 4);
        float wa = __expf(pa), wb = __expf(pb), wc = __expf(pc), wd = __expf(pd);
        lsum += (wa + wb) + (wc + wd);
        a0 += wa * blo(va.x) + wb * blo(vb.x) + wc * blo(vc.x) + wd * blo(vd.x);
        a1 += wa * bhi(va.x) + wb * bhi(vb.x) + wc * bhi(vc.x) + wd * bhi(vd.x);
        a2 += wa * blo(va.y) + wb * blo(vb.y) + wc * blo(vc.y) + wd * blo(vd.y);
        a3 += wa * bhi(va.y) + wb * bhi(vb.y) + wc * bhi(vc.y) + wd * bhi(vd.y);
    }
    for (; pos < s1; pos += 2) {              // tail: 1 edge per half, predicated
        int e = pos + half;
        bool ok = e < s1;
        int sa = csr_src[ok ? e : (s1 - 1)];
        const unsigned* ra = Cu + (long)sa * 256;
        unsigned ka = ra[128 + sl];
        uint2 va = *(const uint2*)(ra + 160 + 2 * sl);
        fx2 a01 = __builtin_amdgcn_cvt_pk_f32_fp8((int)ka, false);
        fx2 a23 = __builtin_amdgcn_cvt_pk_f32_fp8((int)ka, true);
        float pa = q4.x * a01.x + q4.y * a01.y + q4.z * a23.x + q4.w * a23.y;
        pa += __shfl_xor(pa, 1); pa += __shfl_xor(pa, 2); pa += __shfl_xor(pa, 4);
        float wa = ok ? __expf(pa) : 0.f;
        lsum += wa;
        a0 += wa * blo(va.x);
        a1 += wa * bhi(va.x);
        a2 += wa * blo(va.y);
        a3 += wa * bhi(va.y);
    }
    lsum += __shfl_xor(lsum, 32);
    a0 += __shfl_xor(a0, 32);
    a1 += __shfl_xor(a1, 32);
    a2 += __shfl_xor(a2, 32);
    a3 += __shfl_xor(a3, 32);
    if (lane < 32) {
        float inv = 1.f / (lsum + 1e-8f);
        float4 o;
        o.x = a0 * inv; o.y = a1 * inv; o.z = a2 * inv; o.w = a3 * inv;
        *(float4*)&agg[(long)d * 128 + 4 * sl] = o;
    }
}

// Output GEMM (fp32): out = relu(A[M x 128] @ B[128 x 128]^T + bias)
__global__ __launch_bounds__(256) void k_gemm(const float* __restrict__ A,
                                              const float* __restrict__ B,
                                              const float* __restrict__ bias,
                                              float* __restrict__ Cp, int M) {
    __shared__ float As[32][64];
    __shared__ float Bs[32][64];
    const int m0 = blockIdx.x * 64, n0 = blockIdx.y * 64;
    const int t = threadIdx.x;
    const int tm = (t & 15) * 4, tn = (t >> 4) * 4;
    float acc[4][4] = {};
    for (int k0 = 0; k0 < 128; k0 += 32) {
#pragma unroll
        for (int i = 0; i < 2; ++i) {
            int idx = t + i * 256;
            int row = idx >> 3;
            int c4 = (idx & 7) * 4;
            float4 fa = make_float4(0.f, 0.f, 0.f, 0.f);
            if (m0 + row < M) fa = *(const float4*)&A[(long)(m0 + row) * 128 + k0 + c4];
            As[c4 + 0][row] = fa.x; As[c4 + 1][row] = fa.y;
            As[c4 + 2][row] = fa.z; As[c4 + 3][row] = fa.w;
            float4 fb = *(const float4*)&B[(long)(n0 + row) * 128 + k0 + c4];
            Bs[c4 + 0][row] = fb.x; Bs[c4 + 1][row] = fb.y;
            Bs[c4 + 2][row] = fb.z; Bs[c4 + 3][row] = fb.w;
        }
        __syncthreads();
#pragma unroll
        for (int k = 0; k < 32; ++k) {
            float4 a = *(const float4*)&As[k][tm];
            float4 b = *(const float4*)&Bs[k][tn];
            acc[0][0] += a.x * b.x; acc[0][1] += a.x * b.y; acc[0][2] += a.x * b.z; acc[0][3] += a.x * b.w;
            acc[1][0] += a.y * b.x; acc[1][1] += a.y * b.y; acc[1][2] += a.y * b.z; acc[1][3] += a.y * b.w;
            acc[2][0] += a.z * b.x; acc[2][1] += a.z * b.y; acc[2][2] += a.z * b.z; acc[2][3] += a.z * b.w;
            acc[3][0] += a.w * b.x; acc[3][1] += a.w * b.y; acc[3][2] += a.w * b.z; acc[3][3] += a.w * b.w;
        }
        __syncthreads();
    }
    float4 bv4 = *(const float4*)&bias[n0 + tn];
#pragma unroll
    for (int i = 0; i < 4; ++i) {
        int m = m0 + tm + i;
        if (m >= M) continue;
        float4 o;
        o.x = fmaxf(acc[i][0] + bv4.x, 0.f); o.y = fmaxf(acc[i][1] + bv4.y, 0.f);
        o.z = fmaxf(acc[i][2] + bv4.z, 0.f); o.w = fmaxf(acc[i][3] + bv4.w, 0.f);
        *(float4*)&Cp[(long)m * 128 + n0 + tn] = o;
    }
}

extern "C" void kernel_launch(void* const* d_in, const int* in_sizes, int n_in,
                              void* d_out, int out_size, void* d_ws, size_t ws_size,
                              hipStream_t stream) {
    const float* x  = (const float*)d_in[0];
    const int* edge = (const int*)d_in[1];
    const float* Wq = (const float*)d_in[2];
    const float* bq = (const float*)d_in[3];
    const float* Wk = (const float*)d_in[4];
    const float* bk = (const float*)d_in[5];
    const float* Wv = (const float*)d_in[6];
    const float* bv = (const float*)d_in[7];
    const float* Wo = (const float*)d_in[8];
    const float* bo = (const float*)d_in[9];
    float* out = (float*)d_out;

    char* ws = (char*)d_ws;
    unsigned short* Wcatb = (unsigned short*)(ws + OFF_WCATB);
    float* bcat      = (float*)(ws + OFF_BCAT);
    unsigned short* xb = (unsigned short*)(ws + OFF_XB);
    unsigned* Cu     = (unsigned*)(ws + OFF_C);
    unsigned short* csr_src = (unsigned short*)(ws + OFF_SRC);
    unsigned short* rank16  = (unsigned short*)(ws + OFF_RANK);
    int*   row_start = (int*)(ws + OFF_RS);
    int*   counts    = (int*)(ws + OFF_CNT);
    int*   bsum      = (int*)(ws + OFF_BSUM);
    float* agg       = (float*)(ws + OFF_AGG);

    const int* srcA = edge;
    const int* dstA = edge + N_EDGES;

    // D1: x->bf16, zero counts, pack weights (one kernel)
    k_prep<<<CVT_NB + ZERO_NB + PREPW_NB, 256, 0, stream>>>(
        x, xb, counts, Wq, bq, Wk, bk, Wv, bv, Wcatb, bcat);

    // D2: QKV projection (MFMA) interleaved 3:4 with dst histogram(+rank)
    k_gemmqkv_hist<<<GQH_GRID, 256, 0, stream>>>(
        xb, Wcatb, bcat, Cu, N_NODES, dstA, counts, rank16);

    // D3: scan -> row_start, then atomic-free fill
    k_scanA<<<SCAN_NB, 256, 0, stream>>>(counts, bsum);
    k_scanB<<<1, 256, 0, stream>>>(bsum, SCAN_NB);
    k_scanC<<<SCAN_NB, 256, 0, stream>>>(counts, bsum, row_start);
    k_fill<<<(N_EDGES + 255) / 256, 256, 0, stream>>>(srcA, dstA, row_start, rank16, csr_src);

    // D4: fused scores + softmax + V aggregate (half-wave, fp8 K, 8-edge batch)
    k_attn<<<(N_NODES + 3) / 4, 256, 0, stream>>>(Cu, row_start, csr_src, agg);

    // D5: out = relu(agg @ Wo^T + bo)
    k_gemm<<<dim3((N_NODES + 63) / 64, 2), 256, 0, stream>>>(agg, Wo, bo, out, N_NODES);
}

// Round 13
// 286.958 us; speedup vs baseline: 1.1471x; 1.0911x over previous
//
#include <hip/hip_runtime.h>

#define N_NODES 50000
#define N_EDGES 1600000
#define DIM 128
#define M_PAD 50048    // 782 * 64
#define NBKT 196       // buckets = dst >> 8
#define CHUNK 6250     // edges per build block
#define BB 256         // build blocks (BB * CHUNK == N_EDGES)

// ---------------- workspace layout (bytes) ----------------
// C layout per node: 1024 B = [Q: 128 fp32 | u32 0..127][K: 128 fp8 | u32 128..159]
//                             [V: 128 bf16 | u32 160..223][pad u32 224..255]
#define OFF_WCATB  0UL                    // 384*128*2   = 98304
#define OFF_BCAT   98304UL                // 384*4       = 1536
#define OFF_XB     99840UL                // 50048*128*2 = 12812288
#define OFF_C      12912128UL             // 50000*1024  = 51200000
#define OFF_SRC    64112128UL             // 1600000*2   = 3200000   (csr src ids, u16)
#define OFF_BKD    67312128UL             // 1600000*4   = 6400000   (bucketed (dloc<<16)|src)
#define OFF_CNT    73712128UL             // 196*256*4   = 200704    (per-(bucket,block) counts/offsets)
#define OFF_BSUM   73912832UL             // 196*4
#define OFF_BOFF   73913664UL             // 197*4       (bucket offsets)
#define OFF_RS     73914496UL             // 50001*4
#define OFF_AGG    74114560UL             // 50000*128*4 = 25600000  -> total ~99.7 MB

typedef __attribute__((ext_vector_type(8))) short short8;    // 8 bf16
typedef __attribute__((ext_vector_type(4))) float floatx4;   // MFMA acc
typedef __attribute__((ext_vector_type(2))) float fx2;       // packed fp8 cvt result

__device__ __forceinline__ unsigned bf16r(float f) {   // fp32 -> bf16 bits, RNE
    unsigned u = __float_as_uint(f);
    return (u + 0x7fffu + ((u >> 16) & 1u)) >> 16;
}
__device__ __forceinline__ unsigned pack2(float a, float b) {
    return bf16r(a) | (bf16r(b) << 16);
}
__device__ __forceinline__ float blo(unsigned v) { return __uint_as_float(v << 16); }
__device__ __forceinline__ float bhi(unsigned v) { return __uint_as_float(v & 0xffff0000u); }

// ---- D1: coarse bucket hist (LDS) | x->bf16 cvt | weight prep ----
#define CVT_NB 6250
#define PREPW_NB 192
#define PREP_GRID (BB + CVT_NB + PREPW_NB)   // 6698
__global__ __launch_bounds__(256) void k_prep(const float* __restrict__ x,
                                              unsigned short* __restrict__ xb,
                                              const float* __restrict__ Wq, const float* __restrict__ bq,
                                              const float* __restrict__ Wk, const float* __restrict__ bk,
                                              const float* __restrict__ Wv, const float* __restrict__ bv,
                                              unsigned short* __restrict__ Wcatb,
                                              float* __restrict__ bcat,
                                              const int* __restrict__ dstA,
                                              int* __restrict__ cnt) {
    __shared__ int h[NBKT];
    int bx = blockIdx.x, t = threadIdx.x;
    if (bx < BB) {                       // coarse hist: 196 LDS bins
        if (t < NBKT) h[t] = 0;
        __syncthreads();
        int base = bx * CHUNK;
        for (int i = t; i < CHUNK; i += 256)
            atomicAdd(&h[dstA[base + i] >> 8], 1);
        __syncthreads();
        if (t < NBKT) cnt[t * BB + bx] = h[t];
    } else if (bx < BB + CVT_NB) {       // cvt: one float4 per thread
        int i = (bx - BB) * 256 + t;
        if (i < N_NODES * DIM / 4) {
            float4 f = ((const float4*)x)[i];
            ushort4 o;
            o.x = (unsigned short)bf16r(f.x); o.y = (unsigned short)bf16r(f.y);
            o.z = (unsigned short)bf16r(f.z); o.w = (unsigned short)bf16r(f.w);
            ((ushort4*)xb)[i] = o;
        }
    } else {                             // weight prep
        int i = (bx - BB - CVT_NB) * 256 + t;
        if (i < 3 * DIM * DIM) {
            int ro = i >> 7, col = i & 127;
            const float* W = (ro < 128) ? Wq : (ro < 256) ? Wk : Wv;
            Wcatb[i] = (unsigned short)bf16r(W[(ro & 127) * DIM + col]);
        }
        if (i < 3 * DIM) {
            const float* b = (i < 128) ? bq : (i < 256) ? bk : bv;
            bcat[i] = b[i & 127];
        }
    }
}

// ---- tiny scans over the 196x256 count matrix ----
__global__ __launch_bounds__(256) void k_b2a(const int* __restrict__ cnt, int* __restrict__ bsum) {
    __shared__ int red[256];
    int t = threadIdx.x;
    red[t] = cnt[blockIdx.x * BB + t];
    __syncthreads();
    for (int off = 128; off > 0; off >>= 1) {
        if (t < off) red[t] += red[t + off];
        __syncthreads();
    }
    if (t == 0) bsum[blockIdx.x] = red[0];
}
__global__ __launch_bounds__(256) void k_b2b(const int* __restrict__ bsum, int* __restrict__ bktoff) {
    __shared__ int s[256];
    int t = threadIdx.x;
    int v = (t < NBKT) ? bsum[t] : 0;
    s[t] = v;
    __syncthreads();
    for (int off = 1; off < 256; off <<= 1) {
        int u = (t >= off) ? s[t - off] : 0;
        __syncthreads();
        s[t] += u;
        __syncthreads();
    }
    if (t < NBKT) bktoff[t] = s[t] - v;
    if (t == NBKT - 1) bktoff[NBKT] = s[t];
}
__global__ __launch_bounds__(256) void k_b2c(int* __restrict__ cnt, const int* __restrict__ bktoff) {
    __shared__ int s[256];
    int t = threadIdx.x;
    int v = cnt[blockIdx.x * BB + t];
    s[t] = v;
    __syncthreads();
    for (int off = 1; off < 256; off <<= 1) {
        int u = (t >= off) ? s[t - off] : 0;
        __syncthreads();
        s[t] += u;
        __syncthreads();
    }
    cnt[blockIdx.x * BB + t] = bktoff[blockIdx.x] + s[t] - v;   // absolute offset
}

// ---- D3: QKV MFMA GEMM interleaved 18:1 with bucket scatter (no global atomics) ----
#define GQ_MB (M_PAD / 64)          // 782
#define GQ_BLOCKS (GQ_MB * 6)       // 4692
#define GB3_GRPS 261
#define GB3_GRID (GB3_GRPS * 19)    // 4959
__global__ __launch_bounds__(256) void k_gemmqkv_b3(const unsigned short* __restrict__ xb,
                                                    const unsigned short* __restrict__ Wb,
                                                    const float* __restrict__ bias,
                                                    unsigned* __restrict__ Cu, int M,
                                                    const int* __restrict__ srcA,
                                                    const int* __restrict__ dstA,
                                                    const int* __restrict__ cnt,
                                                    unsigned* __restrict__ bucketed) {
    __shared__ __align__(16) unsigned short As[64][136];
    __shared__ __align__(16) unsigned short Bs[64][136];
    __shared__ int cur[NBKT];
    const int grp = blockIdx.x / 19, r = blockIdx.x % 19;
    const int t = threadIdx.x;
    if (r == 18) {                      // bucket scatter block
        if (grp < BB) {
            if (t < NBKT) cur[t] = cnt[t * BB + grp];
            __syncthreads();
            int base = grp * CHUNK;
            for (int i = t; i < CHUNK; i += 256) {
                int e = base + i;
                int d = dstA[e];
                int p = atomicAdd(&cur[d >> 8], 1);       // LDS
                bucketed[p] = (unsigned)srcA[e] | ((unsigned)(d & 255) << 16);
            }
        }
        return;
    }
    const int g = grp * 18 + r;
    if (g >= GQ_BLOCKS) return;
    const int m0 = (g % GQ_MB) * 64, n0 = (g / GQ_MB) * 64;
    {
        int row = t >> 2, ch = t & 3;
        const uint4* xrow = (const uint4*)(xb + (long)(m0 + row) * 128);
        const uint4* wrow = (const uint4*)(Wb + (long)(n0 + row) * 128);
#pragma unroll
        for (int j = 0; j < 4; ++j) {
            *(uint4*)&As[row][(ch + 4 * j) * 8] = xrow[ch + 4 * j];
            *(uint4*)&Bs[row][(ch + 4 * j) * 8] = wrow[ch + 4 * j];
        }
    }
    __syncthreads();
    const int w = t >> 6, lane = t & 63;
    const int quad = lane >> 4, c = lane & 15;
    floatx4 acc[4] = {{0.f,0.f,0.f,0.f},{0.f,0.f,0.f,0.f},{0.f,0.f,0.f,0.f},{0.f,0.f,0.f,0.f}};
#pragma unroll
    for (int ks = 0; ks < 4; ++ks) {
        short8 a = *(const short8*)&As[w * 16 + c][ks * 32 + quad * 8];
#pragma unroll
        for (int nt = 0; nt < 4; ++nt) {
            short8 b = *(const short8*)&Bs[nt * 16 + c][ks * 32 + quad * 8];
            acc[nt] = __builtin_amdgcn_mfma_f32_16x16x32_bf16(a, b, acc[nt], 0, 0, 0);
        }
    }
#pragma unroll
    for (int nt = 0; nt < 4; ++nt) {
        int gn = n0 + nt * 16 + c;
        float bv = bias[gn];
        int slice = gn >> 7;           // 0=Q 1=K(fp8) 2=V(bf16)
        int cs = gn & 127;
#pragma unroll
        for (int i = 0; i < 4; ++i) {
            int gm = m0 + w * 16 + quad * 4 + i;
            float o = acc[nt][i] + bv;
            float f1 = __shfl_xor(o, 1);
            float f2 = __shfl_xor(o, 2);
            float f3 = __shfl_xor(o, 3);
            if (gm < M) {
                unsigned* crow = Cu + (long)gm * 256;
                if (slice == 0) {
                    ((float*)crow)[cs] = o;
                } else if (slice == 1) {
                    if ((c & 3) == 0) {
                        int pk = __builtin_amdgcn_cvt_pk_fp8_f32(o, f1, 0, false);
                        pk = __builtin_amdgcn_cvt_pk_fp8_f32(f2, f3, pk, true);
                        crow[128 + (cs >> 2)] = (unsigned)pk;
                    }
                } else {
                    if ((c & 1) == 0) crow[160 + (cs >> 1)] = pack2(o, f1);
                }
            }
        }
    }
}

// ---- D4: per-bucket fine sort -> csr_src + row_start (all LDS atomics) ----
__global__ __launch_bounds__(256) void k_b4(const unsigned* __restrict__ bucketed,
                                            const int* __restrict__ bktoff,
                                            unsigned short* __restrict__ csr_src,
                                            int* __restrict__ row_start) {
    __shared__ int h[256], s[256], cur[256];
    int b = blockIdx.x, t = threadIdx.x;
    int base = bktoff[b], end = bktoff[b + 1];
    h[t] = 0;
    __syncthreads();
    for (int p = base + t; p < end; p += 256)
        atomicAdd(&h[bucketed[p] >> 16], 1);
    __syncthreads();
    int v = h[t];
    s[t] = v;
    __syncthreads();
    for (int off = 1; off < 256; off <<= 1) {
        int u = (t >= off) ? s[t - off] : 0;
        __syncthreads();
        s[t] += u;
        __syncthreads();
    }
    int start = base + s[t] - v;
    int d = b * 256 + t;
    if (d < N_NODES) row_start[d] = start;
    if (d == N_NODES - 1) row_start[N_NODES] = N_EDGES;
    cur[t] = start;
    __syncthreads();
    for (int p = base + t; p < end; p += 256) {
        unsigned u = bucketed[p];
        int q = atomicAdd(&cur[u >> 16], 1);              // LDS
        csr_src[q] = (unsigned short)(u & 0xffffu);
    }
}

// ---- fused scores+softmax+aggregate, half-wave layout, no max shift ----
__global__ __launch_bounds__(256) void k_attn(const unsigned* __restrict__ Cu,
                                              const int* __restrict__ row_start,
                                              const unsigned short* __restrict__ csr_src,
                                              float* __restrict__ agg) {
    int d = blockIdx.x * 4 + (threadIdx.x >> 6);
    int lane = threadIdx.x & 63;
    if (d >= N_NODES) return;
    const int half = lane >> 5, sl = lane & 31;
    const float scale = 0.17677669529663687f;   // 1/sqrt(32), folded into q
    float4 q4 = *(const float4*)((const float*)(Cu + (long)d * 256) + 4 * sl);
    q4.x *= scale; q4.y *= scale; q4.z *= scale; q4.w *= scale;
    int s0 = row_start[d], s1 = row_start[d + 1];
    float lsum = 0.f, a0 = 0.f, a1 = 0.f, a2 = 0.f, a3 = 0.f;
    int pos = s0;
    for (; pos + 8 <= s1; pos += 8) {         // 4 edges per half
        int base = pos + half * 4;
        int sa = csr_src[base + 0];
        int sb = csr_src[base + 1];
        int sc2 = csr_src[base + 2];
        int sd = csr_src[base + 3];
        const unsigned* ra = Cu + (long)sa * 256;
        const unsigned* rb = Cu + (long)sb * 256;
        const unsigned* rc = Cu + (long)sc2 * 256;
        const unsigned* rd = Cu + (long)sd * 256;
        unsigned ka = ra[128 + sl];
        unsigned kb = rb[128 + sl];
        unsigned kc = rc[128 + sl];
        unsigned kd = rd[128 + sl];
        uint2 va = *(const uint2*)(ra + 160 + 2 * sl);
        uint2 vb = *(const uint2*)(rb + 160 + 2 * sl);
        uint2 vc = *(const uint2*)(rc + 160 + 2 * sl);
        uint2 vd = *(const uint2*)(rd + 160 + 2 * sl);
        fx2 a01 = __builtin_amdgcn_cvt_pk_f32_fp8((int)ka, false);
        fx2 a23 = __builtin_amdgcn_cvt_pk_f32_fp8((int)ka, true);
        fx2 b01 = __builtin_amdgcn_cvt_pk_f32_fp8((int)kb, false);
        fx2 b23 = __builtin_amdgcn_cvt_pk_f32_fp8((int)kb, true);
        fx2 c01 = __builtin_amdgcn_cvt_pk_f32_fp8((int)kc, false);
        fx2 c23 = __builtin_amdgcn_cvt_pk_f32_fp8((int)kc, true);
        fx2 d01 = __builtin_amdgcn_cvt_pk_f32_fp8((int)kd, false);
        fx2 d23 = __builtin_amdgcn_cvt_pk_f32_fp8((int)kd, true);
        float pa = q4.x * a01.x + q4.y * a01.y + q4.z * a23.x + q4.w * a23.y;
        float pb = q4.x * b01.x + q4.y * b01.y + q4.z * b23.x + q4.w * b23.y;
        float pc = q4.x * c01.x + q4.y * c01.y + q4.z * c23.x + q4.w * c23.y;
        float pd = q4.x * d01.x + q4.y * d01.y + q4.z * d23.x + q4.w * d23.y;
        pa += __shfl_xor(pa, 1); pa += __shfl_xor(pa, 2); pa += __shfl_xor(pa, 4);
        pb += __shfl_xor(pb, 1); pb += __shfl_xor(pb, 2); pb += __shfl_xor(pb, 4);
        pc += __shfl_xor(pc, 1); pc += __shfl_xor(pc, 2); pc += __shfl_xor(pc, 4);
        pd += __shfl_xor(pd, 1); pd += __shfl_xor(pd, 2); pd += __shfl_xor(pd, 4);
        float wa = __expf(pa), wb = __expf(pb), wc = __expf(pc), wd = __expf(pd);
        lsum += (wa + wb) + (wc + wd);
        a0 += wa * blo(va.x) + wb * blo(vb.x) + wc * blo(vc.x) + wd * blo(vd.x);
        a1 += wa * bhi(va.x) + wb * bhi(vb.x) + wc * bhi(vc.x) + wd * bhi(vd.x);
        a2 += wa * blo(va.y) + wb * blo(vb.y) + wc * blo(vc.y) + wd * blo(vd.y);
        a3 += wa * bhi(va.y) + wb * bhi(vb.y) + wc * bhi(vc.y) + wd * bhi(vd.y);
    }
    for (; pos < s1; pos += 2) {              // tail: 1 edge per half, predicated
        int e = pos + half;
        bool ok = e < s1;
        int sa = csr_src[ok ? e : (s1 - 1)];
        const unsigned* ra = Cu + (long)sa * 256;
        unsigned ka = ra[128 + sl];
        uint2 va = *(const uint2*)(ra + 160 + 2 * sl);
        fx2 a01 = __builtin_amdgcn_cvt_pk_f32_fp8((int)ka, false);
        fx2 a23 = __builtin_amdgcn_cvt_pk_f32_fp8((int)ka, true);
        float pa = q4.x * a01.x + q4.y * a01.y + q4.z * a23.x + q4.w * a23.y;
        pa += __shfl_xor(pa, 1); pa += __shfl_xor(pa, 2); pa += __shfl_xor(pa, 4);
        float wa = ok ? __expf(pa) : 0.f;
        lsum += wa;
        a0 += wa * blo(va.x);
        a1 += wa * bhi(va.x);
        a2 += wa * blo(va.y);
        a3 += wa * bhi(va.y);
    }
    lsum += __shfl_xor(lsum, 32);
    a0 += __shfl_xor(a0, 32);
    a1 += __shfl_xor(a1, 32);
    a2 += __shfl_xor(a2, 32);
    a3 += __shfl_xor(a3, 32);
    if (lane < 32) {
        float inv = 1.f / (lsum + 1e-8f);
        float4 o;
        o.x = a0 * inv; o.y = a1 * inv; o.z = a2 * inv; o.w = a3 * inv;
        *(float4*)&agg[(long)d * 128 + 4 * sl] = o;
    }
}

// Output GEMM (fp32): out = relu(A[M x 128] @ B[128 x 128]^T + bias)
__global__ __launch_bounds__(256) void k_gemm(const float* __restrict__ A,
                                              const float* __restrict__ B,
                                              const float* __restrict__ bias,
                                              float* __restrict__ Cp, int M) {
    __shared__ float As[32][64];
    __shared__ float Bs[32][64];
    const int m0 = blockIdx.x * 64, n0 = blockIdx.y * 64;
    const int t = threadIdx.x;
    const int tm = (t & 15) * 4, tn = (t >> 4) * 4;
    float acc[4][4] = {};
    for (int k0 = 0; k0 < 128; k0 += 32) {
#pragma unroll
        for (int i = 0; i < 2; ++i) {
            int idx = t + i * 256;
            int row = idx >> 3;
            int c4 = (idx & 7) * 4;
            float4 fa = make_float4(0.f, 0.f, 0.f, 0.f);
            if (m0 + row < M) fa = *(const float4*)&A[(long)(m0 + row) * 128 + k0 + c4];
            As[c4 + 0][row] = fa.x; As[c4 + 1][row] = fa.y;
            As[c4 + 2][row] = fa.z; As[c4 + 3][row] = fa.w;
            float4 fb = *(const float4*)&B[(long)(n0 + row) * 128 + k0 + c4];
            Bs[c4 + 0][row] = fb.x; Bs[c4 + 1][row] = fb.y;
            Bs[c4 + 2][row] = fb.z; Bs[c4 + 3][row] = fb.w;
        }
        __syncthreads();
#pragma unroll
        for (int k = 0; k < 32; ++k) {
            float4 a = *(const float4*)&As[k][tm];
            float4 b = *(const float4*)&Bs[k][tn];
            acc[0][0] += a.x * b.x; acc[0][1] += a.x * b.y; acc[0][2] += a.x * b.z; acc[0][3] += a.x * b.w;
            acc[1][0] += a.y * b.x; acc[1][1] += a.y * b.y; acc[1][2] += a.y * b.z; acc[1][3] += a.y * b.w;
            acc[2][0] += a.z * b.x; acc[2][1] += a.z * b.y; acc[2][2] += a.z * b.z; acc[2][3] += a.z * b.w;
            acc[3][0] += a.w * b.x; acc[3][1] += a.w * b.y; acc[3][2] += a.w * b.z; acc[3][3] += a.w * b.w;
        }
        __syncthreads();
    }
    float4 bv4 = *(const float4*)&bias[n0 + tn];
#pragma unroll
    for (int i = 0; i < 4; ++i) {
        int m = m0 + tm + i;
        if (m >= M) continue;
        float4 o;
        o.x = fmaxf(acc[i][0] + bv4.x, 0.f); o.y = fmaxf(acc[i][1] + bv4.y, 0.f);
        o.z = fmaxf(acc[i][2] + bv4.z, 0.f); o.w = fmaxf(acc[i][3] + bv4.w, 0.f);
        *(float4*)&Cp[(long)m * 128 + n0 + tn] = o;
    }
}

extern "C" void kernel_launch(void* const* d_in, const int* in_sizes, int n_in,
                              void* d_out, int out_size, void* d_ws, size_t ws_size,
                              hipStream_t stream) {
    const float* x  = (const float*)d_in[0];
    const int* edge = (const int*)d_in[1];
    const float* Wq = (const float*)d_in[2];
    const float* bq = (const float*)d_in[3];
    const float* Wk = (const float*)d_in[4];
    const float* bk = (const float*)d_in[5];
    const float* Wv = (const float*)d_in[6];
    const float* bv = (const float*)d_in[7];
    const float* Wo = (const float*)d_in[8];
    const float* bo = (const float*)d_in[9];
    float* out = (float*)d_out;

    char* ws = (char*)d_ws;
    unsigned short* Wcatb = (unsigned short*)(ws + OFF_WCATB);
    float* bcat      = (float*)(ws + OFF_BCAT);
    unsigned short* xb = (unsigned short*)(ws + OFF_XB);
    unsigned* Cu     = (unsigned*)(ws + OFF_C);
    unsigned short* csr_src = (unsigned short*)(ws + OFF_SRC);
    unsigned* bucketed = (unsigned*)(ws + OFF_BKD);
    int*   cnt       = (int*)(ws + OFF_CNT);
    int*   bsum      = (int*)(ws + OFF_BSUM);
    int*   bktoff    = (int*)(ws + OFF_BOFF);
    int*   row_start = (int*)(ws + OFF_RS);
    float* agg       = (float*)(ws + OFF_AGG);

    const int* srcA = edge;
    const int* dstA = edge + N_EDGES;

    // D1: coarse bucket hist (LDS) || x->bf16 || weight prep
    k_prep<<<PREP_GRID, 256, 0, stream>>>(
        x, xb, Wq, bq, Wk, bk, Wv, bv, Wcatb, bcat, dstA, cnt);

    // D2: tiny scans -> per-(bucket,block) absolute offsets
    k_b2a<<<NBKT, 256, 0, stream>>>(cnt, bsum);
    k_b2b<<<1, 256, 0, stream>>>(bsum, bktoff);
    k_b2c<<<NBKT, 256, 0, stream>>>(cnt, bktoff);

    // D3: QKV MFMA GEMM || bucket scatter (LDS cursors)
    k_gemmqkv_b3<<<GB3_GRID, 256, 0, stream>>>(
        xb, Wcatb, bcat, Cu, N_NODES, srcA, dstA, cnt, bucketed);

    // D4: per-bucket fine counting sort -> csr_src + row_start
    k_b4<<<NBKT, 256, 0, stream>>>(bucketed, bktoff, csr_src, row_start);

    // D5: fused scores + softmax + V aggregate
    k_attn<<<(N_NODES + 3) / 4, 256, 0, stream>>>(Cu, row_start, csr_src, agg);

    // D6: out = relu(agg @ Wo^T + bo)
    k_gemm<<<dim3((N_NODES + 63) / 64, 2), 256, 0, stream>>>(agg, Wo, bo, out, N_NODES);
}